// Round 8
// baseline (869.661 us; speedup 1.0000x reference)
//
#include <hip/hip_runtime.h>

#define NGRAPH 256
#define NNODE  512
#define KNN    6
#define NCAND  12
#define NF     64
#define ST     68                  // fp32 row stride (floats), 272B (16B-aligned)
#define SBF    72                  // bf16 row stride (shorts), 144B (16B-aligned)
#define TBS    20                  // filter tile buffer row stride (floats)
#define NT     1024
// filter-phase layout (lives INSIDE the X region, dead after filter):
#define SQF    18432               // xbf = 512*72 shorts = 18432 floats at [0,18432)
#define TB0    18944               // 16 waves x 16x20 = 5120 floats -> ends 24064
// persistent scratch above X region:
#define SCR    (NNODE*ST)          // 34816
#define CANDF  SCR                 // cand: 512*12 ushort = 12288B = 3072 floats
#define SQX    (SCR + 3072)        // exact fp32 sq, 512 floats
#define LDS_FLOATS (SCR + 3584)    // 38400 floats
#define LDS_BYTES  (LDS_FLOATS*4)  // 153600 B < 160 KiB
// pool/head scratch reuses the (dead) cand region after refine:
#define POOLP  CANDF               // 16*64 partials
#define POOLED (CANDF + 1024)      // 64
#define Y1OFF  (CANDF + 1088)      // 256
#define Y2OFF  (CANDF + 1344)     // 256
#define Y3OFF  (CANDF + 1600)     // 64
#define BIG 1e30f

typedef float v4f __attribute__((ext_vector_type(4)));
typedef short v8s __attribute__((ext_vector_type(8)));

struct Params {
  const float *x;
  const float *W1,*b1,*a1, *W2,*b2,*a2;
  const float *Wc0,*bc0, *Wc1,*bc1, *Wc2,*bc2, *Wc3,*bc3;
  const float *W3,*b3,*a3, *W4,*b4,*a4;
  const float *Wh1,*bh1, *Wh2,*bh2, *Wh3,*bh3, *Wh4,*bh4;
  float *out;
};

// fp32 -> bf16 (RNE) as raw ushort
__device__ __forceinline__ unsigned f2bf(float x) {
  union { float f; unsigned u; } cc; cc.f = x;
  unsigned u = cc.u;
  return (u + 0x7FFFu + ((u >> 16) & 1u)) >> 16;
}

__device__ __forceinline__ v8s bfrag(const unsigned short* xbf, int row, int c0) {
  return *(const v8s*)(xbf + row*SBF + c0);
}

// half-row GEMM: acc[o] = sum_k row[k]*W[k*64+o], o in [0,32) of a pre-offset W.
// row per-lane-ish (2-lane broadcast); W wave-uniform -> s_load + v_fmac v,s,v.
__device__ __forceinline__ void gemm32(const float* row, const float* W, float* acc) {
#pragma unroll
  for (int o = 0; o < 32; ++o) acc[o] = 0.f;
#pragma unroll 1
  for (int k4 = 0; k4 < 16; ++k4) {
    float4 xv = *(const float4*)(row + 4*k4);
    const float* w = W + 4*k4*NF;
#pragma unroll
    for (int o = 0; o < 32; ++o) acc[o] = fmaf(xv.x, w[o],        acc[o]);
#pragma unroll
    for (int o = 0; o < 32; ++o) acc[o] = fmaf(xv.y, w[NF+o],     acc[o]);
#pragma unroll
    for (int o = 0; o < 32; ++o) acc[o] = fmaf(xv.z, w[2*NF+o],   acc[o]);
#pragma unroll
    for (int o = 0; o < 32; ++o) acc[o] = fmaf(xv.w, w[3*NF+o],   acc[o]);
  }
}

// linear+PReLU on own (row, col-half); cross-wave safe via barriers
__device__ __forceinline__ void linear_half(float* lds, int rA, int half,
                                            const float* W, const float* b, const float* a) {
  float acc[32];
  gemm32(&lds[rA*ST], W + 32*half, acc);
  __syncthreads();                       // all reads of h done before any write
  const float* bb = b + 32*half;
  const float* aa = a + 32*half;
  float* row = &lds[rA*ST + 32*half];
#pragma unroll
  for (int o4 = 0; o4 < 8; ++o4) {
    float t0 = acc[4*o4+0] + bb[4*o4+0];
    float t1 = acc[4*o4+1] + bb[4*o4+1];
    float t2 = acc[4*o4+2] + bb[4*o4+2];
    float t3 = acc[4*o4+3] + bb[4*o4+3];
    float4 v;
    v.x = t0 >= 0.f ? t0 : aa[4*o4+0]*t0;
    v.y = t1 >= 0.f ? t1 : aa[4*o4+1]*t1;
    v.z = t2 >= 0.f ? t2 : aa[4*o4+2]*t2;
    v.w = t3 >= 0.f ? t3 : aa[4*o4+3]*t3;
    *(float4*)(row + 4*o4) = v;
  }
  __syncthreads();                       // writes visible before next reads
}

// sorted-ascending top-8 insert; strict <
__device__ __forceinline__ void insert8(float (&b)[8], int (&bi)[8], float v, int vi) {
  if (v < b[7]) {
#pragma unroll
    for (int p = 0; p < 8; ++p) {
      bool lt = v < b[p];
      float tb = b[p]; int ti = bi[p];
      b[p]  = lt ? v  : tb;  bi[p] = lt ? vi : ti;
      v     = lt ? tb : v;   vi    = lt ? ti : vi;
    }
  }
}

// sorted-ascending top-12 insert; strict <
__device__ __forceinline__ void insert12(float (&b)[NCAND], int (&bi)[NCAND], float v, int vi) {
  if (v < b[NCAND-1]) {
#pragma unroll
    for (int p = 0; p < NCAND; ++p) {
      bool lt = v < b[p];
      float tb = b[p]; int ti = bi[p];
      b[p]  = lt ? v  : tb;  bi[p] = lt ? vi : ti;
      v     = lt ? tb : v;   vi    = lt ? ti : vi;
    }
  }
}

__global__ __launch_bounds__(NT) void fused_gnn(Params P) {
  extern __shared__ float lds[];
  unsigned short* xbf   = (unsigned short*)lds;
  unsigned short* candU = (unsigned short*)&lds[CANDF];
  const int tid  = threadIdx.x;
  const int g    = blockIdx.x;
  const int rA   = tid & 511;           // layer-phase row
  const int half = tid >> 9;            // layer-phase col half (wave-uniform)

  const float4* xg = (const float4*)(P.x + (size_t)g * NNODE * NF);

  // ---- stage x[g] as bf16 into xbf ----
#pragma unroll 1
  for (int i = tid; i < NNODE*NF/4; i += NT) {
    float4 v = xg[i];
    int row = i >> 4, k4 = i & 15;
    unsigned lo = f2bf(v.x) | (f2bf(v.y) << 16);
    unsigned hi = f2bf(v.z) | (f2bf(v.w) << 16);
    uint2 pk = {lo, hi};
    *(uint2*)&xbf[row*SBF + 4*k4] = pk;
  }
  __syncthreads();

  // ---- filter sq from bf16 values ----
  if (tid < 512) {
    const unsigned* xr32 = (const unsigned*)(xbf + tid*SBF);
    float s = 0.f;
#pragma unroll
    for (int k = 0; k < 32; ++k) {
      unsigned u = xr32[k];
      union { unsigned u; float f; } c0, c1;
      c0.u = u << 16; c1.u = u & 0xffff0000u;
      s = fmaf(c0.f, c0.f, s);
      s = fmaf(c1.f, c1.f, s);
    }
    lds[SQF + tid] = s;
  }
  __syncthreads();

  // ==== kNN filter: bf16 MFMA Gram + per-wave tile transpose + lane-local top-8 ====
  {
    const int lane = tid & 63;
    const int w    = tid >> 6;          // wave 0..15
    const int c    = lane & 15;
    const int qq   = lane >> 4;         // 0..3
    float* tb = &lds[TB0 + w*16*TBS];   // per-wave 16x20 tile buffer

#pragma unroll 1
    for (int p = 0; p < 2; ++p) {
      const int i0 = (p*16 + w) * 16;
      v8s A0 = bfrag(xbf, i0 + c, qq*8);
      v8s A1 = bfrag(xbf, i0 + c, 32 + qq*8);
      const int myrow = i0 + c;

      float d8[8]; int i8[8];
#pragma unroll
      for (int m = 0; m < 8; ++m) { d8[m] = BIG; i8[m] = 0; }

#pragma unroll 1
      for (int jt = 0; jt < 32; ++jt) {
        const int j0 = jt * 16;
        v8s B0 = bfrag(xbf, j0 + c, qq*8);
        v8s B1 = bfrag(xbf, j0 + c, 32 + qq*8);
        v4f acc = {0.f, 0.f, 0.f, 0.f};
        acc = __builtin_amdgcn_mfma_f32_16x16x32_bf16(A0, B0, acc, 0, 0, 0);
        acc = __builtin_amdgcn_mfma_f32_16x16x32_bf16(A1, B1, acc, 0, 0, 0);
#pragma unroll
        for (int r = 0; r < 4; ++r) tb[(qq*4 + r)*TBS + c] = acc[r];
        float4 dv = *(const float4*)&tb[c*TBS + qq*4];
        float4 sv = *(const float4*)&lds[SQF + j0 + qq*4];
        float e0 = fmaf(-2.f, dv.x, sv.x);
        float e1 = fmaf(-2.f, dv.y, sv.y);
        float e2 = fmaf(-2.f, dv.z, sv.z);
        float e3 = fmaf(-2.f, dv.w, sv.w);
        const int jb = j0 + qq*4;
        if (jb     == myrow) e0 = BIG;
        if (jb + 1 == myrow) e1 = BIG;
        if (jb + 2 == myrow) e2 = BIG;
        if (jb + 3 == myrow) e3 = BIG;
        insert8(d8, i8, e0, jb);
        insert8(d8, i8, e1, jb+1);
        insert8(d8, i8, e2, jb+2);
        insert8(d8, i8, e3, jb+3);
      }

      // merge across the 4 qq-lanes sharing this row: 2 butterfly stages
      float cd[NCAND]; int ci[NCAND];
#pragma unroll
      for (int m = 0; m < 8; ++m) { cd[m] = d8[m]; ci[m] = i8[m]; }
#pragma unroll
      for (int m = 8; m < NCAND; ++m) { cd[m] = BIG; ci[m] = 0; }
      {
        float pd[8]; int pi[8];
#pragma unroll
        for (int s = 0; s < 8; ++s) { pd[s] = __shfl_xor(cd[s], 16); pi[s] = __shfl_xor(ci[s], 16); }
#pragma unroll
        for (int s = 0; s < 8; ++s) insert12(cd, ci, pd[s], pi[s]);
      }
      {
        float pd[NCAND]; int pi[NCAND];
#pragma unroll
        for (int s = 0; s < NCAND; ++s) { pd[s] = __shfl_xor(cd[s], 32); pi[s] = __shfl_xor(ci[s], 32); }
#pragma unroll
        for (int s = 0; s < NCAND; ++s) insert12(cd, ci, pd[s], pi[s]);
      }
      if (lane < 16) {
#pragma unroll
        for (int s = 0; s < NCAND; ++s) candU[(i0 + lane)*NCAND + s] = (unsigned short)ci[s];
      }
    }
  }
  __syncthreads();

  // ---- restage fp32 X (L2/L3-warm), overwrites xbf/sqf/tilebuf ----
#pragma unroll 1
  for (int i = tid; i < NNODE*NF/4; i += NT) {
    float4 v = xg[i];
    int row = i >> 4, k4 = i & 15;
    *(float4*)&lds[row*ST + 4*k4] = v;
  }
  __syncthreads();

  // ---- exact fp32 sq ----
  if (tid < 512) {
    float s0 = 0.f;
#pragma unroll
    for (int k4 = 0; k4 < 16; ++k4) {
      float4 a = *(const float4*)&lds[tid*ST + 4*k4];
      s0 = fmaf(a.x,a.x,s0); s0 = fmaf(a.y,a.y,s0); s0 = fmaf(a.z,a.z,s0); s0 = fmaf(a.w,a.w,s0);
    }
    lds[SQX + tid] = s0;
  }
  __syncthreads();

  // ==== exact fp32 re-rank of 12 candidates (R3-identical math; duplicated per half) ====
  int nbrA[KNN];
  {
    float4 xr16[16];
#pragma unroll
    for (int k4 = 0; k4 < 16; ++k4)
      xr16[k4] = *(const float4*)&lds[rA*ST + 4*k4];

    float nd[6]; int ni[6];
#pragma unroll
    for (int m = 0; m < 6; ++m) { nd[m] = BIG; ni[m] = 0x7fffffff; }

    int cnd[NCAND];
#pragma unroll
    for (int s = 0; s < NCAND; ++s) cnd[s] = candU[rA*NCAND + s];

#pragma unroll 1
    for (int s = 0; s < NCAND; ++s) {
      int j = cnd[s];
      const float* xj = &lds[j*ST];
      float4 aa = {0.f, 0.f, 0.f, 0.f};
#pragma unroll
      for (int k4 = 0; k4 < 16; ++k4) {
        float4 v = *(const float4*)(xj + 4*k4);
        aa.x = fmaf(xr16[k4].x, v.x, aa.x); aa.y = fmaf(xr16[k4].y, v.y, aa.y);
        aa.z = fmaf(xr16[k4].z, v.z, aa.z); aa.w = fmaf(xr16[k4].w, v.w, aa.w);
      }
      float e = fmaf(-2.f, (aa.x+aa.y)+(aa.z+aa.w), lds[SQX + j]);
      if (e < nd[5] || (e == nd[5] && j < ni[5])) {
#pragma unroll
        for (int pp = 0; pp < 6; ++pp) {
          bool lt = (e < nd[pp]) || (e == nd[pp] && j < ni[pp]);
          float tb = nd[pp]; int ti = ni[pp];
          nd[pp] = lt ? e : tb;  ni[pp] = lt ? j : ti;
          e      = lt ? tb : e;  j      = lt ? ti : j;
        }
      }
    }
#pragma unroll
    for (int m = 0; m < 6; ++m) nbrA[m] = ni[m];
  }
  __syncthreads();   // refine reads done before layers overwrite

  // ---- h = prelu(x@W1+b1); h = prelu(h@W2+b2)  (row, col-half per thread) ----
  linear_half(lds, rA, half, P.W1, P.b1, P.a1);
  linear_half(lds, rA, half, P.W2, P.b2, P.a2);

  // ---- 4x gconv ----
  const float* Wcs[4] = {P.Wc0, P.Wc1, P.Wc2, P.Wc3};
  const float* bcs[4] = {P.bc0, P.bc1, P.bc2, P.bc3};
#pragma unroll 1
  for (int cv = 0; cv < 4; ++cv) {
    const float* W = Wcs[cv] + 32*half;
    const float* b = bcs[cv] + 32*half;
    // snapshot own (row, col-half) of h
    float hs[32];
#pragma unroll
    for (int o4 = 0; o4 < 8; ++o4) {
      float4 v = *(const float4*)&lds[rA*ST + 32*half + 4*o4];
      hs[4*o4]=v.x; hs[4*o4+1]=v.y; hs[4*o4+2]=v.z; hs[4*o4+3]=v.w;
    }
    // p = h @ W (own half)
    float acc[32];
    gemm32(&lds[rA*ST], W, acc);
    __syncthreads();                     // all h reads done
#pragma unroll
    for (int o4 = 0; o4 < 8; ++o4) {
      float4 v = {acc[4*o4], acc[4*o4+1], acc[4*o4+2], acc[4*o4+3]};
      *(float4*)&lds[rA*ST + 32*half + 4*o4] = v;
    }
    __syncthreads();                     // all p published
    // gather own col-half of 6 neighbor p-rows
    float sA[32];
    {
      const float* pr = &lds[nbrA[0]*ST + 32*half];
#pragma unroll
      for (int o4 = 0; o4 < 8; ++o4) {
        float4 v = *(const float4*)(pr + 4*o4);
        sA[4*o4]=v.x; sA[4*o4+1]=v.y; sA[4*o4+2]=v.z; sA[4*o4+3]=v.w;
      }
    }
#pragma unroll
    for (int m = 1; m < KNN; ++m) {
      const float* pr = &lds[nbrA[m]*ST + 32*half];
#pragma unroll
      for (int o4 = 0; o4 < 8; ++o4) {
        float4 v = *(const float4*)(pr + 4*o4);
        sA[4*o4]+=v.x; sA[4*o4+1]+=v.y; sA[4*o4+2]+=v.z; sA[4*o4+3]+=v.w;
      }
    }
    __syncthreads();                     // gathers done before overwrite
#pragma unroll
    for (int o4 = 0; o4 < 8; ++o4) {
      float4 v;
      v.x = sA[4*o4]   + 6.f*b[4*o4]   + hs[4*o4];
      v.y = sA[4*o4+1] + 6.f*b[4*o4+1] + hs[4*o4+1];
      v.z = sA[4*o4+2] + 6.f*b[4*o4+2] + hs[4*o4+2];
      v.w = sA[4*o4+3] + 6.f*b[4*o4+3] + hs[4*o4+3];
      *(float4*)&lds[rA*ST + 32*half + 4*o4] = v;
    }
    __syncthreads();                     // h stable before next conv reads
  }

  // ---- last two PReLU linears ----
  linear_half(lds, rA, half, P.W3, P.b3, P.a3);
  linear_half(lds, rA, half, P.W4, P.b4, P.a4);

  // (linear_half ends with a barrier; h final)

  // ---- global add pool: 16 chunks of 32 rows ----
  {
    int f = tid & 63, c = tid >> 6;      // c in 0..15
    int rstart = c * 32;
    float pa=0.f, pb=0.f, pc=0.f, pd=0.f;
#pragma unroll 1
    for (int r = 0; r < 32; r += 4) {
      pa += lds[(rstart+r  )*ST + f];
      pb += lds[(rstart+r+1)*ST + f];
      pc += lds[(rstart+r+2)*ST + f];
      pd += lds[(rstart+r+3)*ST + f];
    }
    lds[POOLP + c*64 + f] = (pa+pb)+(pc+pd);
  }
  __syncthreads();
  if (tid < 64) {
    float pool = 0.f;
#pragma unroll
    for (int c = 0; c < 16; ++c) pool += lds[POOLP + c*64 + tid];
    lds[POOLED + tid] = pool;
  }
  __syncthreads();

  // ---- head MLP ----
  if (tid < 256) {
    float acc = P.bh1[tid];
#pragma unroll 4
    for (int k = 0; k < 64; ++k) acc = fmaf(lds[POOLED+k], P.Wh1[k*256 + tid], acc);
    lds[Y1OFF + tid] = acc >= 0.f ? acc : 0.2f*acc;
  }
  __syncthreads();
  if (tid < 256) {
    float acc = P.bh2[tid];
#pragma unroll 4
    for (int k = 0; k < 256; ++k) acc = fmaf(lds[Y1OFF+k], P.Wh2[k*256 + tid], acc);
    lds[Y2OFF + tid] = acc >= 0.f ? acc : 0.2f*acc;
  }
  __syncthreads();
  if (tid < 64) {
    float acc = P.bh3[tid];
#pragma unroll 4
    for (int k = 0; k < 256; ++k) acc = fmaf(lds[Y2OFF+k], P.Wh3[k*64 + tid], acc);
    lds[Y3OFF + tid] = acc >= 0.f ? acc : 0.2f*acc;
  }
  __syncthreads();
  if (tid == 0) {
    float acc = P.bh4[0];
#pragma unroll 4
    for (int k = 0; k < 64; ++k) acc = fmaf(lds[Y3OFF+k], P.Wh4[k], acc);
    P.out[g] = acc;
  }
}

extern "C" void kernel_launch(void* const* d_in, const int* in_sizes, int n_in,
                              void* d_out, int out_size, void* d_ws, size_t ws_size,
                              hipStream_t stream) {
  Params P;
  P.x   = (const float*)d_in[0];
  P.W1  = (const float*)d_in[1];  P.b1  = (const float*)d_in[2];  P.a1 = (const float*)d_in[3];
  P.W2  = (const float*)d_in[4];  P.b2  = (const float*)d_in[5];  P.a2 = (const float*)d_in[6];
  P.Wc0 = (const float*)d_in[7];  P.bc0 = (const float*)d_in[8];
  P.Wc1 = (const float*)d_in[9];  P.bc1 = (const float*)d_in[10];
  P.Wc2 = (const float*)d_in[11]; P.bc2 = (const float*)d_in[12];
  P.Wc3 = (const float*)d_in[13]; P.bc3 = (const float*)d_in[14];
  P.W3  = (const float*)d_in[15]; P.b3  = (const float*)d_in[16]; P.a3 = (const float*)d_in[17];
  P.W4  = (const float*)d_in[18]; P.b4  = (const float*)d_in[19]; P.a4 = (const float*)d_in[20];
  P.Wh1 = (const float*)d_in[21]; P.bh1 = (const float*)d_in[22];
  P.Wh2 = (const float*)d_in[23]; P.bh2 = (const float*)d_in[24];
  P.Wh3 = (const float*)d_in[25]; P.bh3 = (const float*)d_in[26];
  P.Wh4 = (const float*)d_in[27]; P.bh4 = (const float*)d_in[28];
  P.out = (float*)d_out;

  (void)hipFuncSetAttribute(reinterpret_cast<const void*>(fused_gnn),
                            hipFuncAttributeMaxDynamicSharedMemorySize, LDS_BYTES);

  fused_gnn<<<NGRAPH, NT, LDS_BYTES, stream>>>(P);
}

// Round 9
// 807.115 us; speedup vs baseline: 1.0775x; 1.0775x over previous
//
#include <hip/hip_runtime.h>

#define NGRAPH 256
#define NNODE  512
#define KNN    6
#define NCAND  12
#define NF     64
#define ST     68                  // fp32 row stride (floats), 272B (16B-aligned)
#define SBF    72                  // bf16 row stride (shorts), 144B (16B-aligned)
#define TBS    20                  // filter tile buffer row stride (floats)
#define NT     1024
// filter-phase layout (lives INSIDE the X region, dead after filter):
#define SQF    18432               // xbf = 512*72 shorts = 18432 floats at [0,18432)
#define TB0    18944               // 16 waves x 16x20 = 5120 floats -> ends 24064
// persistent scratch above X region:
#define SCR    (NNODE*ST)          // 34816
#define CANDF  SCR                 // cand: 512*12 ushort = 12288B = 3072 floats
#define SQX    (SCR + 3072)        // exact fp32 sq, 512 floats
#define LDS_FLOATS (SCR + 3584)    // 38400 floats
#define LDS_BYTES  (LDS_FLOATS*4)  // 153600 B < 160 KiB
// pool/head scratch reuses the (dead) cand region after refine:
#define POOLP  CANDF               // 16*64 partials
#define POOLED (CANDF + 1024)      // 64
#define Y1OFF  (CANDF + 1088)      // 256
#define Y2OFF  (CANDF + 1344)     // 256
#define Y3OFF  (CANDF + 1600)     // 64
#define BIG 1e30f

typedef float v4f __attribute__((ext_vector_type(4)));
typedef short v8s __attribute__((ext_vector_type(8)));

struct Params {
  const float *x;
  const float *W1,*b1,*a1, *W2,*b2,*a2;
  const float *Wc0,*bc0, *Wc1,*bc1, *Wc2,*bc2, *Wc3,*bc3;
  const float *W3,*b3,*a3, *W4,*b4,*a4;
  const float *Wh1,*bh1, *Wh2,*bh2, *Wh3,*bh3, *Wh4,*bh4;
  float *out;
};

// fp32 -> bf16 (RNE) as raw ushort
__device__ __forceinline__ unsigned f2bf(float x) {
  union { float f; unsigned u; } cc; cc.f = x;
  unsigned u = cc.u;
  return (u + 0x7FFFu + ((u >> 16) & 1u)) >> 16;
}

__device__ __forceinline__ v8s bfrag(const unsigned short* xbf, int row, int c0) {
  return *(const v8s*)(xbf + row*SBF + c0);
}

// half-row GEMM: acc[o] = sum_k row[k]*W[k*64+o], o in [0,32) of a pre-offset W.
// row per-lane-ish (2-lane broadcast); W wave-uniform -> s_load + v_fmac v,s,v.
__device__ __forceinline__ void gemm32(const float* row, const float* W, float* acc) {
#pragma unroll
  for (int o = 0; o < 32; ++o) acc[o] = 0.f;
#pragma unroll 1
  for (int k4 = 0; k4 < 16; ++k4) {
    float4 xv = *(const float4*)(row + 4*k4);
    const float* w = W + 4*k4*NF;
#pragma unroll
    for (int o = 0; o < 32; ++o) acc[o] = fmaf(xv.x, w[o],        acc[o]);
#pragma unroll
    for (int o = 0; o < 32; ++o) acc[o] = fmaf(xv.y, w[NF+o],     acc[o]);
#pragma unroll
    for (int o = 0; o < 32; ++o) acc[o] = fmaf(xv.z, w[2*NF+o],   acc[o]);
#pragma unroll
    for (int o = 0; o < 32; ++o) acc[o] = fmaf(xv.w, w[3*NF+o],   acc[o]);
  }
}

// linear+PReLU on own (row, col-half); cross-wave safe via barriers
__device__ __forceinline__ void linear_half(float* lds, int rA, int half,
                                            const float* W, const float* b, const float* a) {
  float acc[32];
  gemm32(&lds[rA*ST], W + 32*half, acc);
  __syncthreads();                       // all reads of h done before any write
  const float* bb = b + 32*half;
  const float* aa = a + 32*half;
  float* row = &lds[rA*ST + 32*half];
#pragma unroll
  for (int o4 = 0; o4 < 8; ++o4) {
    float t0 = acc[4*o4+0] + bb[4*o4+0];
    float t1 = acc[4*o4+1] + bb[4*o4+1];
    float t2 = acc[4*o4+2] + bb[4*o4+2];
    float t3 = acc[4*o4+3] + bb[4*o4+3];
    float4 v;
    v.x = t0 >= 0.f ? t0 : aa[4*o4+0]*t0;
    v.y = t1 >= 0.f ? t1 : aa[4*o4+1]*t1;
    v.z = t2 >= 0.f ? t2 : aa[4*o4+2]*t2;
    v.w = t3 >= 0.f ? t3 : aa[4*o4+3]*t3;
    *(float4*)(row + 4*o4) = v;
  }
  __syncthreads();                       // writes visible before next reads
}

// sorted-ascending top-8 insert; strict <
__device__ __forceinline__ void insert8(float (&b)[8], int (&bi)[8], float v, int vi) {
  if (v < b[7]) {
#pragma unroll
    for (int p = 0; p < 8; ++p) {
      bool lt = v < b[p];
      float tb = b[p]; int ti = bi[p];
      b[p]  = lt ? v  : tb;  bi[p] = lt ? vi : ti;
      v     = lt ? tb : v;   vi    = lt ? ti : vi;
    }
  }
}

// sorted-ascending top-12 insert; strict <
__device__ __forceinline__ void insert12(float (&b)[NCAND], int (&bi)[NCAND], float v, int vi) {
  if (v < b[NCAND-1]) {
#pragma unroll
    for (int p = 0; p < NCAND; ++p) {
      bool lt = v < b[p];
      float tb = b[p]; int ti = bi[p];
      b[p]  = lt ? v  : tb;  bi[p] = lt ? vi : ti;
      v     = lt ? tb : v;   vi    = lt ? ti : vi;
    }
  }
}

__global__ __launch_bounds__(NT)
__attribute__((amdgpu_waves_per_eu(4, 4)))   // pin 4 waves/EU -> VGPR budget 128, no spill
void fused_gnn(Params P) {
  extern __shared__ float lds[];
  unsigned short* xbf   = (unsigned short*)lds;
  unsigned short* candU = (unsigned short*)&lds[CANDF];
  const int tid  = threadIdx.x;
  const int g    = blockIdx.x;
  const int rA   = tid & 511;           // layer-phase row
  const int half = tid >> 9;            // layer-phase col half (wave-uniform)

  const float4* xg = (const float4*)(P.x + (size_t)g * NNODE * NF);

  // ---- stage x[g] as bf16 into xbf ----
#pragma unroll 1
  for (int i = tid; i < NNODE*NF/4; i += NT) {
    float4 v = xg[i];
    int row = i >> 4, k4 = i & 15;
    unsigned lo = f2bf(v.x) | (f2bf(v.y) << 16);
    unsigned hi = f2bf(v.z) | (f2bf(v.w) << 16);
    uint2 pk = {lo, hi};
    *(uint2*)&xbf[row*SBF + 4*k4] = pk;
  }
  __syncthreads();

  // ---- filter sq from bf16 values ----
  if (tid < 512) {
    const unsigned* xr32 = (const unsigned*)(xbf + tid*SBF);
    float s = 0.f;
#pragma unroll
    for (int k = 0; k < 32; ++k) {
      unsigned u = xr32[k];
      union { unsigned u; float f; } c0, c1;
      c0.u = u << 16; c1.u = u & 0xffff0000u;
      s = fmaf(c0.f, c0.f, s);
      s = fmaf(c1.f, c1.f, s);
    }
    lds[SQF + tid] = s;
  }
  __syncthreads();

  // ==== kNN filter: bf16 MFMA Gram + per-wave tile transpose + lane-local top-8 ====
  {
    const int lane = tid & 63;
    const int w    = tid >> 6;          // wave 0..15
    const int c    = lane & 15;
    const int qq   = lane >> 4;         // 0..3
    float* tb = &lds[TB0 + w*16*TBS];   // per-wave 16x20 tile buffer

#pragma unroll 1
    for (int p = 0; p < 2; ++p) {
      const int i0 = (p*16 + w) * 16;
      v8s A0 = bfrag(xbf, i0 + c, qq*8);
      v8s A1 = bfrag(xbf, i0 + c, 32 + qq*8);
      const int myrow = i0 + c;

      float d8[8]; int i8[8];
#pragma unroll
      for (int m = 0; m < 8; ++m) { d8[m] = BIG; i8[m] = 0; }

#pragma unroll 1
      for (int jt = 0; jt < 32; ++jt) {
        const int j0 = jt * 16;
        v8s B0 = bfrag(xbf, j0 + c, qq*8);
        v8s B1 = bfrag(xbf, j0 + c, 32 + qq*8);
        v4f acc = {0.f, 0.f, 0.f, 0.f};
        acc = __builtin_amdgcn_mfma_f32_16x16x32_bf16(A0, B0, acc, 0, 0, 0);
        acc = __builtin_amdgcn_mfma_f32_16x16x32_bf16(A1, B1, acc, 0, 0, 0);
#pragma unroll
        for (int r = 0; r < 4; ++r) tb[(qq*4 + r)*TBS + c] = acc[r];
        float4 dv = *(const float4*)&tb[c*TBS + qq*4];
        float4 sv = *(const float4*)&lds[SQF + j0 + qq*4];
        float e0 = fmaf(-2.f, dv.x, sv.x);
        float e1 = fmaf(-2.f, dv.y, sv.y);
        float e2 = fmaf(-2.f, dv.z, sv.z);
        float e3 = fmaf(-2.f, dv.w, sv.w);
        const int jb = j0 + qq*4;
        if (jb     == myrow) e0 = BIG;
        if (jb + 1 == myrow) e1 = BIG;
        if (jb + 2 == myrow) e2 = BIG;
        if (jb + 3 == myrow) e3 = BIG;
        insert8(d8, i8, e0, jb);
        insert8(d8, i8, e1, jb+1);
        insert8(d8, i8, e2, jb+2);
        insert8(d8, i8, e3, jb+3);
      }

      // merge across the 4 qq-lanes sharing this row: 2 butterfly stages
      float cd[NCAND]; int ci[NCAND];
#pragma unroll
      for (int m = 0; m < 8; ++m) { cd[m] = d8[m]; ci[m] = i8[m]; }
#pragma unroll
      for (int m = 8; m < NCAND; ++m) { cd[m] = BIG; ci[m] = 0; }
      {
        float pd[8]; int pi[8];
#pragma unroll
        for (int s = 0; s < 8; ++s) { pd[s] = __shfl_xor(cd[s], 16); pi[s] = __shfl_xor(ci[s], 16); }
#pragma unroll
        for (int s = 0; s < 8; ++s) insert12(cd, ci, pd[s], pi[s]);
      }
      {
        float pd[NCAND]; int pi[NCAND];
#pragma unroll
        for (int s = 0; s < NCAND; ++s) { pd[s] = __shfl_xor(cd[s], 32); pi[s] = __shfl_xor(ci[s], 32); }
#pragma unroll
        for (int s = 0; s < NCAND; ++s) insert12(cd, ci, pd[s], pi[s]);
      }
      if (lane < 16) {
#pragma unroll
        for (int s = 0; s < NCAND; ++s) candU[(i0 + lane)*NCAND + s] = (unsigned short)ci[s];
      }
    }
  }
  __syncthreads();

  // ---- restage fp32 X (L2/L3-warm), overwrites xbf/sqf/tilebuf ----
#pragma unroll 1
  for (int i = tid; i < NNODE*NF/4; i += NT) {
    float4 v = xg[i];
    int row = i >> 4, k4 = i & 15;
    *(float4*)&lds[row*ST + 4*k4] = v;
  }
  __syncthreads();

  // ---- exact fp32 sq ----
  if (tid < 512) {
    float s0 = 0.f;
#pragma unroll
    for (int k4 = 0; k4 < 16; ++k4) {
      float4 a = *(const float4*)&lds[tid*ST + 4*k4];
      s0 = fmaf(a.x,a.x,s0); s0 = fmaf(a.y,a.y,s0); s0 = fmaf(a.z,a.z,s0); s0 = fmaf(a.w,a.w,s0);
    }
    lds[SQX + tid] = s0;
  }
  __syncthreads();

  // ==== exact fp32 re-rank of 12 candidates (R3-identical math; duplicated per half) ====
  int nbrA[KNN];
  {
    float4 xr16[16];
#pragma unroll
    for (int k4 = 0; k4 < 16; ++k4)
      xr16[k4] = *(const float4*)&lds[rA*ST + 4*k4];

    float nd[6]; int ni[6];
#pragma unroll
    for (int m = 0; m < 6; ++m) { nd[m] = BIG; ni[m] = 0x7fffffff; }

    int cnd[NCAND];
#pragma unroll
    for (int s = 0; s < NCAND; ++s) cnd[s] = candU[rA*NCAND + s];

#pragma unroll 1
    for (int s = 0; s < NCAND; ++s) {
      int j = cnd[s];
      const float* xj = &lds[j*ST];
      float4 aa = {0.f, 0.f, 0.f, 0.f};
#pragma unroll
      for (int k4 = 0; k4 < 16; ++k4) {
        float4 v = *(const float4*)(xj + 4*k4);
        aa.x = fmaf(xr16[k4].x, v.x, aa.x); aa.y = fmaf(xr16[k4].y, v.y, aa.y);
        aa.z = fmaf(xr16[k4].z, v.z, aa.z); aa.w = fmaf(xr16[k4].w, v.w, aa.w);
      }
      float e = fmaf(-2.f, (aa.x+aa.y)+(aa.z+aa.w), lds[SQX + j]);
      if (e < nd[5] || (e == nd[5] && j < ni[5])) {
#pragma unroll
        for (int pp = 0; pp < 6; ++pp) {
          bool lt = (e < nd[pp]) || (e == nd[pp] && j < ni[pp]);
          float tb = nd[pp]; int ti = ni[pp];
          nd[pp] = lt ? e : tb;  ni[pp] = lt ? j : ti;
          e      = lt ? tb : e;  j      = lt ? ti : j;
        }
      }
    }
#pragma unroll
    for (int m = 0; m < 6; ++m) nbrA[m] = ni[m];
  }
  __syncthreads();   // refine reads done before layers overwrite

  // ---- h = prelu(x@W1+b1); h = prelu(h@W2+b2)  (row, col-half per thread) ----
  linear_half(lds, rA, half, P.W1, P.b1, P.a1);
  linear_half(lds, rA, half, P.W2, P.b2, P.a2);

  // ---- 4x gconv ----
  const float* Wcs[4] = {P.Wc0, P.Wc1, P.Wc2, P.Wc3};
  const float* bcs[4] = {P.bc0, P.bc1, P.bc2, P.bc3};
#pragma unroll 1
  for (int cv = 0; cv < 4; ++cv) {
    const float* W = Wcs[cv] + 32*half;
    const float* b = bcs[cv] + 32*half;
    // snapshot own (row, col-half) of h
    float hs[32];
#pragma unroll
    for (int o4 = 0; o4 < 8; ++o4) {
      float4 v = *(const float4*)&lds[rA*ST + 32*half + 4*o4];
      hs[4*o4]=v.x; hs[4*o4+1]=v.y; hs[4*o4+2]=v.z; hs[4*o4+3]=v.w;
    }
    // p = h @ W (own half)
    float acc[32];
    gemm32(&lds[rA*ST], W, acc);
    __syncthreads();                     // all h reads done
#pragma unroll
    for (int o4 = 0; o4 < 8; ++o4) {
      float4 v = {acc[4*o4], acc[4*o4+1], acc[4*o4+2], acc[4*o4+3]};
      *(float4*)&lds[rA*ST + 32*half + 4*o4] = v;
    }
    // fold hs + 6b into the gather accumulator (hs reused; acc dead after store)
#pragma unroll
    for (int o = 0; o < 32; ++o) hs[o] = fmaf(6.f, b[o], hs[o]);
    __syncthreads();                     // all p published
    // gather own col-half of 6 neighbor p-rows into hs
#pragma unroll
    for (int m = 0; m < KNN; ++m) {
      const float* pr = &lds[nbrA[m]*ST + 32*half];
#pragma unroll
      for (int o4 = 0; o4 < 8; ++o4) {
        float4 v = *(const float4*)(pr + 4*o4);
        hs[4*o4]+=v.x; hs[4*o4+1]+=v.y; hs[4*o4+2]+=v.z; hs[4*o4+3]+=v.w;
      }
    }
    __syncthreads();                     // gathers done before overwrite
#pragma unroll
    for (int o4 = 0; o4 < 8; ++o4) {
      float4 v = {hs[4*o4], hs[4*o4+1], hs[4*o4+2], hs[4*o4+3]};
      *(float4*)&lds[rA*ST + 32*half + 4*o4] = v;
    }
    __syncthreads();                     // h stable before next conv reads
  }

  // ---- last two PReLU linears ----
  linear_half(lds, rA, half, P.W3, P.b3, P.a3);
  linear_half(lds, rA, half, P.W4, P.b4, P.a4);

  // (linear_half ends with a barrier; h final)

  // ---- global add pool: 16 chunks of 32 rows ----
  {
    int f = tid & 63, c = tid >> 6;      // c in 0..15
    int rstart = c * 32;
    float pa=0.f, pb=0.f, pc=0.f, pd=0.f;
#pragma unroll 1
    for (int r = 0; r < 32; r += 4) {
      pa += lds[(rstart+r  )*ST + f];
      pb += lds[(rstart+r+1)*ST + f];
      pc += lds[(rstart+r+2)*ST + f];
      pd += lds[(rstart+r+3)*ST + f];
    }
    lds[POOLP + c*64 + f] = (pa+pb)+(pc+pd);
  }
  __syncthreads();
  if (tid < 64) {
    float pool = 0.f;
#pragma unroll
    for (int c = 0; c < 16; ++c) pool += lds[POOLP + c*64 + tid];
    lds[POOLED + tid] = pool;
  }
  __syncthreads();

  // ---- head MLP ----
  if (tid < 256) {
    float acc = P.bh1[tid];
#pragma unroll 4
    for (int k = 0; k < 64; ++k) acc = fmaf(lds[POOLED+k], P.Wh1[k*256 + tid], acc);
    lds[Y1OFF + tid] = acc >= 0.f ? acc : 0.2f*acc;
  }
  __syncthreads();
  if (tid < 256) {
    float acc = P.bh2[tid];
#pragma unroll 4
    for (int k = 0; k < 256; ++k) acc = fmaf(lds[Y1OFF+k], P.Wh2[k*256 + tid], acc);
    lds[Y2OFF + tid] = acc >= 0.f ? acc : 0.2f*acc;
  }
  __syncthreads();
  if (tid < 64) {
    float acc = P.bh3[tid];
#pragma unroll 4
    for (int k = 0; k < 256; ++k) acc = fmaf(lds[Y2OFF+k], P.Wh3[k*64 + tid], acc);
    lds[Y3OFF + tid] = acc >= 0.f ? acc : 0.2f*acc;
  }
  __syncthreads();
  if (tid == 0) {
    float acc = P.bh4[0];
#pragma unroll 4
    for (int k = 0; k < 64; ++k) acc = fmaf(lds[Y3OFF+k], P.Wh4[k], acc);
    P.out[g] = acc;
  }
}

extern "C" void kernel_launch(void* const* d_in, const int* in_sizes, int n_in,
                              void* d_out, int out_size, void* d_ws, size_t ws_size,
                              hipStream_t stream) {
  Params P;
  P.x   = (const float*)d_in[0];
  P.W1  = (const float*)d_in[1];  P.b1  = (const float*)d_in[2];  P.a1 = (const float*)d_in[3];
  P.W2  = (const float*)d_in[4];  P.b2  = (const float*)d_in[5];  P.a2 = (const float*)d_in[6];
  P.Wc0 = (const float*)d_in[7];  P.bc0 = (const float*)d_in[8];
  P.Wc1 = (const float*)d_in[9];  P.bc1 = (const float*)d_in[10];
  P.Wc2 = (const float*)d_in[11]; P.bc2 = (const float*)d_in[12];
  P.Wc3 = (const float*)d_in[13]; P.bc3 = (const float*)d_in[14];
  P.W3  = (const float*)d_in[15]; P.b3  = (const float*)d_in[16]; P.a3 = (const float*)d_in[17];
  P.W4  = (const float*)d_in[18]; P.b4  = (const float*)d_in[19]; P.a4 = (const float*)d_in[20];
  P.Wh1 = (const float*)d_in[21]; P.bh1 = (const float*)d_in[22];
  P.Wh2 = (const float*)d_in[23]; P.bh2 = (const float*)d_in[24];
  P.Wh3 = (const float*)d_in[25]; P.bh3 = (const float*)d_in[26];
  P.Wh4 = (const float*)d_in[27]; P.bh4 = (const float*)d_in[28];
  P.out = (float*)d_out;

  (void)hipFuncSetAttribute(reinterpret_cast<const void*>(fused_gnn),
                            hipFuncAttributeMaxDynamicSharedMemorySize, LDS_BYTES);

  fused_gnn<<<NGRAPH, NT, LDS_BYTES, stream>>>(P);
}

// Round 11
// 407.824 us; speedup vs baseline: 2.1324x; 1.9791x over previous
//
#include <hip/hip_runtime.h>

#define NGRAPH 256
#define NNODE  512
#define KNN    6
#define NCAND  12
#define NF     64
#define SBF    72                 // bf16 row stride in shorts (144 B, 16B-aligned)
#define TBS    20                 // filter tile buffer row stride (floats)
#define NT     512
// LDS layout (float indices):
#define PBF    18432              // hbf = 512*72 shorts = 18432 floats at [0,PBF)
                                  // pbf = 512*72 shorts at [PBF, 36864)
#define CANDO  PBF                // cand: 512*12 ushort = 3072 floats (dead before convs)
#define SQO    (PBF + 3072)       // 512 floats (bf16 sq, then exact sq; dead before convs)
#define TBO    (PBF + 3584)       // 8 waves x 16x20 = 2560 floats (dead after filter)
#define WTO    36864              // Wt bf16: 64*72 shorts = 2304 floats
#define LDS_FLOATS 39168
#define LDS_BYTES  (LDS_FLOATS*4) // 156672 B < 160 KiB
// pool/head scratch (pbf region, dead after last conv gather):
#define POOLP  PBF
#define POOLED (PBF + 512)
#define Y1OFF  (PBF + 576)
#define Y2OFF  (PBF + 832)
#define Y3OFF  (PBF + 1088)
#define BIG 1e30f

typedef float v4f __attribute__((ext_vector_type(4)));
typedef short v8s __attribute__((ext_vector_type(8)));

struct Params {
  const float *x;
  const float *W1,*b1,*a1, *W2,*b2,*a2;
  const float *Wc0,*bc0, *Wc1,*bc1, *Wc2,*bc2, *Wc3,*bc3;
  const float *W3,*b3,*a3, *W4,*b4,*a4;
  const float *Wh1,*bh1, *Wh2,*bh2, *Wh3,*bh3, *Wh4,*bh4;
  float *out;
};

// fp32 -> bf16 (RNE) as raw 16-bit
__device__ __forceinline__ unsigned f2bf(float x) {
  union { float f; unsigned u; } cc; cc.f = x;
  unsigned u = cc.u;
  return (u + 0x7FFFu + ((u >> 16) & 1u)) >> 16;
}
__device__ __forceinline__ float bflo(unsigned u) {  // low short -> fp32
  union { unsigned u; float f; } c; c.u = u << 16; return c.f;
}
__device__ __forceinline__ float bfhi(unsigned u) {  // high short -> fp32
  union { unsigned u; float f; } c; c.u = u & 0xffff0000u; return c.f;
}

__device__ __forceinline__ v8s bfrag(const unsigned short* base, int row, int c0) {
  return *(const v8s*)(base + row*SBF + c0);
}

// sorted-ascending top-8 insert; strict <
__device__ __forceinline__ void insert8(float (&b)[8], int (&bi)[8], float v, int vi) {
  if (v < b[7]) {
#pragma unroll
    for (int p = 0; p < 8; ++p) {
      bool lt = v < b[p];
      float tb = b[p]; int ti = bi[p];
      b[p]  = lt ? v  : tb;  bi[p] = lt ? vi : ti;
      v     = lt ? tb : v;   vi    = lt ? ti : vi;
    }
  }
}
// sorted-ascending top-12 insert; strict <
__device__ __forceinline__ void insert12(float (&b)[NCAND], int (&bi)[NCAND], float v, int vi) {
  if (v < b[NCAND-1]) {
#pragma unroll
    for (int p = 0; p < NCAND; ++p) {
      bool lt = v < b[p];
      float tb = b[p]; int ti = bi[p];
      b[p]  = lt ? v  : tb;  bi[p] = lt ? vi : ti;
      v     = lt ? tb : v;   vi    = lt ? ti : vi;
    }
  }
}

// stage W^T as bf16 into Wt: Wt[col][k] = bf16(W[k*64+col]); one b128 write/thread
__device__ __forceinline__ void stage_wt(const float* W, unsigned short* wt, int tid) {
  const int col = tid >> 3, ks = (tid & 7) * 8;
  const float* wp = W + col;
  unsigned d[4];
#pragma unroll
  for (int i = 0; i < 4; ++i) {
    unsigned lo = f2bf(wp[(ks + 2*i    ) * NF]);
    unsigned hi = f2bf(wp[(ks + 2*i + 1) * NF]);
    d[i] = lo | (hi << 16);
  }
  *(uint4*)&wt[col*SBF + ks] = make_uint4(d[0], d[1], d[2], d[3]);
}

__global__ __launch_bounds__(NT) void fused_gnn(Params P) {
  extern __shared__ float lds[];
  unsigned short* hbf  = (unsigned short*)lds;                 // 512 x SBF bf16
  unsigned short* pbf  = (unsigned short*)&lds[PBF];           // 512 x SBF bf16
  unsigned short* wt   = (unsigned short*)&lds[WTO];           // 64 x SBF bf16 (W^T)
  unsigned short* cand = (unsigned short*)&lds[CANDO];
  const int tid  = threadIdx.x;
  const int g    = blockIdx.x;
  const int rA   = tid;                  // row ownership (512 threads = 512 rows)
  const int lane = tid & 63;
  const int w    = tid >> 6;             // wave 0..7
  const int c    = lane & 15;
  const int qq   = lane >> 4;            // 0..3

  const float* xgp = P.x + (size_t)g * NNODE * NF;
  const float4* xg = (const float4*)xgp;

  // ---- stage x[g] as bf16 into hbf ----
#pragma unroll 1
  for (int i = tid; i < NNODE*NF/4; i += NT) {
    float4 v = xg[i];
    int row = i >> 4, k4 = i & 15;
    unsigned lo = f2bf(v.x) | (f2bf(v.y) << 16);
    unsigned hi = f2bf(v.z) | (f2bf(v.w) << 16);
    *(uint2*)&hbf[row*SBF + 4*k4] = make_uint2(lo, hi);
  }
  __syncthreads();

  // ---- filter sq from bf16 values ----
  {
    const unsigned* xr32 = (const unsigned*)(hbf + rA*SBF);
    float s = 0.f;
#pragma unroll
    for (int k = 0; k < 32; ++k) {
      unsigned u = xr32[k];
      float f0 = bflo(u), f1 = bfhi(u);
      s = fmaf(f0, f0, s);
      s = fmaf(f1, f1, s);
    }
    lds[SQO + rA] = s;
  }
  __syncthreads();

  // ==== kNN filter: bf16 MFMA Gram + per-wave tile transpose + lane-local top-8 ====
  {
    float* tb = &lds[TBO + w*16*TBS];
#pragma unroll 1
    for (int p = 0; p < 4; ++p) {
      const int i0 = (p*8 + w) * 16;
      v8s A0 = bfrag(hbf, i0 + c, qq*8);
      v8s A1 = bfrag(hbf, i0 + c, 32 + qq*8);
      const int myrow = i0 + c;

      float d8[8]; int i8[8];
#pragma unroll
      for (int m = 0; m < 8; ++m) { d8[m] = BIG; i8[m] = 0; }

#pragma unroll 1
      for (int jt = 0; jt < 32; ++jt) {
        const int j0 = jt * 16;
        v8s B0 = bfrag(hbf, j0 + c, qq*8);
        v8s B1 = bfrag(hbf, j0 + c, 32 + qq*8);
        v4f acc = {0.f, 0.f, 0.f, 0.f};
        acc = __builtin_amdgcn_mfma_f32_16x16x32_bf16(A0, B0, acc, 0, 0, 0);
        acc = __builtin_amdgcn_mfma_f32_16x16x32_bf16(A1, B1, acc, 0, 0, 0);
#pragma unroll
        for (int r = 0; r < 4; ++r) tb[(qq*4 + r)*TBS + c] = acc[r];
        float4 dv = *(const float4*)&tb[c*TBS + qq*4];
        float4 sv = *(const float4*)&lds[SQO + j0 + qq*4];
        float e0 = fmaf(-2.f, dv.x, sv.x);
        float e1 = fmaf(-2.f, dv.y, sv.y);
        float e2 = fmaf(-2.f, dv.z, sv.z);
        float e3 = fmaf(-2.f, dv.w, sv.w);
        const int jb = j0 + qq*4;
        if (jb     == myrow) e0 = BIG;
        if (jb + 1 == myrow) e1 = BIG;
        if (jb + 2 == myrow) e2 = BIG;
        if (jb + 3 == myrow) e3 = BIG;
        insert8(d8, i8, e0, jb);
        insert8(d8, i8, e1, jb+1);
        insert8(d8, i8, e2, jb+2);
        insert8(d8, i8, e3, jb+3);
      }

      float cd[NCAND]; int ci[NCAND];
#pragma unroll
      for (int m = 0; m < 8; ++m) { cd[m] = d8[m]; ci[m] = i8[m]; }
#pragma unroll
      for (int m = 8; m < NCAND; ++m) { cd[m] = BIG; ci[m] = 0; }
      {
        float pd[8]; int pi[8];
#pragma unroll
        for (int s = 0; s < 8; ++s) { pd[s] = __shfl_xor(cd[s], 16); pi[s] = __shfl_xor(ci[s], 16); }
#pragma unroll
        for (int s = 0; s < 8; ++s) insert12(cd, ci, pd[s], pi[s]);
      }
      {
        float pd[NCAND]; int pi[NCAND];
#pragma unroll
        for (int s = 0; s < NCAND; ++s) { pd[s] = __shfl_xor(cd[s], 32); pi[s] = __shfl_xor(ci[s], 32); }
#pragma unroll
        for (int s = 0; s < NCAND; ++s) insert12(cd, ci, pd[s], pi[s]);
      }
      if (lane < 16) {
#pragma unroll
        for (int s = 0; s < NCAND; ++s) cand[(i0 + lane)*NCAND + s] = (unsigned short)ci[s];
      }
    }
  }
  __syncthreads();   // filter done; SQO safe to overwrite

  // ==== exact fp32 refine from GLOBAL x (L1/L2-warm) — indices identical to R6 ====
  int nbrA[KNN];
  {
    float4 xr16[16];
    const float4* xrow = (const float4*)(xgp + rA*NF);
#pragma unroll
    for (int k4 = 0; k4 < 16; ++k4) xr16[k4] = xrow[k4];
    {
      float s0 = 0.f;
#pragma unroll
      for (int k4 = 0; k4 < 16; ++k4) {
        float4 a = xr16[k4];
        s0 = fmaf(a.x,a.x,s0); s0 = fmaf(a.y,a.y,s0); s0 = fmaf(a.z,a.z,s0); s0 = fmaf(a.w,a.w,s0);
      }
      lds[SQO + rA] = s0;
    }
    __syncthreads();   // exact sq published

    float nd[6]; int ni[6];
#pragma unroll
    for (int m = 0; m < 6; ++m) { nd[m] = BIG; ni[m] = 0x7fffffff; }
    int cnd[NCAND];
#pragma unroll
    for (int s = 0; s < NCAND; ++s) cnd[s] = cand[rA*NCAND + s];

#pragma unroll 1
    for (int s = 0; s < NCAND; ++s) {
      int j = cnd[s];
      const float4* xj = (const float4*)(xgp + j*NF);
      float4 aa = {0.f, 0.f, 0.f, 0.f};
#pragma unroll
      for (int k4 = 0; k4 < 16; ++k4) {
        float4 v = xj[k4];
        aa.x = fmaf(xr16[k4].x, v.x, aa.x); aa.y = fmaf(xr16[k4].y, v.y, aa.y);
        aa.z = fmaf(xr16[k4].z, v.z, aa.z); aa.w = fmaf(xr16[k4].w, v.w, aa.w);
      }
      float e = fmaf(-2.f, (aa.x+aa.y)+(aa.z+aa.w), lds[SQO + j]);
      if (e < nd[5] || (e == nd[5] && j < ni[5])) {
#pragma unroll
        for (int pp = 0; pp < 6; ++pp) {
          bool lt = (e < nd[pp]) || (e == nd[pp] && j < ni[pp]);
          float tb = nd[pp]; int ti = ni[pp];
          nd[pp] = lt ? e : tb;  ni[pp] = lt ? j : ti;
          e      = lt ? tb : e;  j      = lt ? ti : j;
        }
      }
    }
#pragma unroll
    for (int m = 0; m < 6; ++m) nbrA[m] = ni[m];
  }

  // ==== layers: bf16 MFMA GEMMs ====
  const float* Ws[8]  = {P.W1, P.W2, P.Wc0, P.Wc1, P.Wc2, P.Wc3, P.W3, P.W4};
  const float* bs[8]  = {P.b1, P.b2, P.bc0, P.bc1, P.bc2, P.bc3, P.b3, P.b4};
  const float* as[8]  = {P.a1, P.a2, 0,     0,     0,     0,     P.a3, P.a4};

#pragma unroll 1
  for (int L = 0; L < 8; ++L) {
    const bool isconv = (L >= 2 && L <= 5);
    __syncthreads();                   // prior layer h stable / Wt reads done
    stage_wt(Ws[L], wt, tid);
    __syncthreads();                   // Wt ready

    // B-fragments (W^T rows = W cols), reused across M-tiles
    v8s B0[4], B1[4];
#pragma unroll
    for (int n = 0; n < 4; ++n) {
      B0[n] = bfrag(wt, n*16 + c, qq*8);
      B1[n] = bfrag(wt, n*16 + c, 32 + qq*8);
    }
    float br[4], ar[4];
    if (!isconv) {
#pragma unroll
      for (int n = 0; n < 4; ++n) { br[n] = bs[L][n*16 + c]; ar[n] = as[L][n*16 + c]; }
    }

#pragma unroll 1
    for (int m = 0; m < 4; ++m) {
      const int i0 = w*64 + m*16;
      v8s A0 = bfrag(hbf, i0 + c, qq*8);
      v8s A1 = bfrag(hbf, i0 + c, 32 + qq*8);
#pragma unroll
      for (int n = 0; n < 4; ++n) {
        v4f acc = {0.f, 0.f, 0.f, 0.f};
        acc = __builtin_amdgcn_mfma_f32_16x16x32_bf16(A0, B0[n], acc, 0, 0, 0);
        acc = __builtin_amdgcn_mfma_f32_16x16x32_bf16(A1, B1[n], acc, 0, 0, 0);
        if (isconv) {
#pragma unroll
          for (int r = 0; r < 4; ++r)
            pbf[(i0 + qq*4 + r)*SBF + n*16 + c] = (unsigned short)f2bf(acc[r]);
        } else {
#pragma unroll
          for (int r = 0; r < 4; ++r) {
            float v = acc[r] + br[n];
            v = v >= 0.f ? v : ar[n]*v;
            hbf[(i0 + qq*4 + r)*SBF + n*16 + c] = (unsigned short)f2bf(v);
          }
        }
      }
    }

    if (isconv) {
      __syncthreads();                 // all p published (and all h A-reads done)
      // gather: h_i + 6b + sum of 6 neighbor p-rows (fp32 accumulate, ALL 64 feats)
      float acc[NF];
      const unsigned* hr = (const unsigned*)&hbf[rA*SBF];
#pragma unroll
      for (int kk = 0; kk < 32; ++kk) {        // 32 uints = 64 bf16 features
        unsigned u = hr[kk];
        acc[2*kk]   = bflo(u);
        acc[2*kk+1] = bfhi(u);
      }
      {
        const float4* bp = (const float4*)bs[L];
#pragma unroll
        for (int o4 = 0; o4 < 16; ++o4) {
          float4 bv = bp[o4];
          acc[4*o4]   = fmaf(6.f, bv.x, acc[4*o4]);
          acc[4*o4+1] = fmaf(6.f, bv.y, acc[4*o4+1]);
          acc[4*o4+2] = fmaf(6.f, bv.z, acc[4*o4+2]);
          acc[4*o4+3] = fmaf(6.f, bv.w, acc[4*o4+3]);
        }
      }
#pragma unroll
      for (int mm = 0; mm < KNN; ++mm) {
        const unsigned* pr = (const unsigned*)&pbf[nbrA[mm]*SBF];
#pragma unroll
        for (int kk = 0; kk < 32; ++kk) {      // 32 uints = 64 features
          unsigned u = pr[kk];
          acc[2*kk]   += bflo(u);
          acc[2*kk+1] += bfhi(u);
        }
      }
      // write back own h row as bf16 (all 64 features)
      unsigned* hw = (unsigned*)&hbf[rA*SBF];
#pragma unroll
      for (int kk = 0; kk < 32; ++kk)
        hw[kk] = f2bf(acc[2*kk]) | (f2bf(acc[2*kk+1]) << 16);
    }
  }
  __syncthreads();   // h final

  // ---- global add pool: pooled[f] = sum_rows h[r][f] (bf16 rows, fp32 sum) ----
  {
    int f = tid & 63, cch = tid >> 6;      // cch 0..7
    int rstart = cch * 64;
    float s = 0.f;
#pragma unroll 1
    for (int r = 0; r < 64; ++r) {
      unsigned u = hbf[(rstart + r)*SBF + f];
      union { unsigned u; float ff; } cv; cv.u = u << 16;
      s += cv.ff;
    }
    lds[POOLP + cch*64 + f] = s;
  }
  __syncthreads();
  if (tid < 64) {
    float pool = 0.f;
#pragma unroll
    for (int cc = 0; cc < 8; ++cc) pool += lds[POOLP + cc*64 + tid];
    lds[POOLED + tid] = pool;
  }
  __syncthreads();

  // ---- head MLP (fp32) ----
  if (tid < 256) {
    float acc = P.bh1[tid];
#pragma unroll 4
    for (int k = 0; k < 64; ++k) acc = fmaf(lds[POOLED+k], P.Wh1[k*256 + tid], acc);
    lds[Y1OFF + tid] = acc >= 0.f ? acc : 0.2f*acc;
  }
  __syncthreads();
  if (tid < 256) {
    float acc = P.bh2[tid];
#pragma unroll 4
    for (int k = 0; k < 256; ++k) acc = fmaf(lds[Y1OFF+k], P.Wh2[k*256 + tid], acc);
    lds[Y2OFF + tid] = acc >= 0.f ? acc : 0.2f*acc;
  }
  __syncthreads();
  if (tid < 64) {
    float acc = P.bh3[tid];
#pragma unroll 4
    for (int k = 0; k < 256; ++k) acc = fmaf(lds[Y2OFF+k], P.Wh3[k*64 + tid], acc);
    lds[Y3OFF + tid] = acc >= 0.f ? acc : 0.2f*acc;
  }
  __syncthreads();
  if (tid == 0) {
    float acc = P.bh4[0];
#pragma unroll 4
    for (int k = 0; k < 64; ++k) acc = fmaf(lds[Y3OFF+k], P.Wh4[k], acc);
    P.out[g] = acc;
  }
}

extern "C" void kernel_launch(void* const* d_in, const int* in_sizes, int n_in,
                              void* d_out, int out_size, void* d_ws, size_t ws_size,
                              hipStream_t stream) {
  Params P;
  P.x   = (const float*)d_in[0];
  P.W1  = (const float*)d_in[1];  P.b1  = (const float*)d_in[2];  P.a1 = (const float*)d_in[3];
  P.W2  = (const float*)d_in[4];  P.b2  = (const float*)d_in[5];  P.a2 = (const float*)d_in[6];
  P.Wc0 = (const float*)d_in[7];  P.bc0 = (const float*)d_in[8];
  P.Wc1 = (const float*)d_in[9];  P.bc1 = (const float*)d_in[10];
  P.Wc2 = (const float*)d_in[11]; P.bc2 = (const float*)d_in[12];
  P.Wc3 = (const float*)d_in[13]; P.bc3 = (const float*)d_in[14];
  P.W3  = (const float*)d_in[15]; P.b3  = (const float*)d_in[16]; P.a3 = (const float*)d_in[17];
  P.W4  = (const float*)d_in[18]; P.b4  = (const float*)d_in[19]; P.a4 = (const float*)d_in[20];
  P.Wh1 = (const float*)d_in[21]; P.bh1 = (const float*)d_in[22];
  P.Wh2 = (const float*)d_in[23]; P.bh2 = (const float*)d_in[24];
  P.Wh3 = (const float*)d_in[25]; P.bh3 = (const float*)d_in[26];
  P.Wh4 = (const float*)d_in[27]; P.bh4 = (const float*)d_in[28];
  P.out = (float*)d_out;

  (void)hipFuncSetAttribute(reinterpret_cast<const void*>(fused_gnn),
                            hipFuncAttributeMaxDynamicSharedMemorySize, LDS_BYTES);

  fused_gnn<<<NGRAPH, NT, LDS_BYTES, stream>>>(P);
}

// Round 12
// 385.131 us; speedup vs baseline: 2.2581x; 1.0589x over previous
//
#include <hip/hip_runtime.h>

#define NGRAPH 256
#define NNODE  512
#define KNN    6
#define NCAND  12
#define NF     64
#define SBF    72                 // bf16 row stride in shorts (144 B, 16B-aligned)
#define TBS    20                 // filter tile buffer row stride (floats)
#define NT     768
#define NW     12                 // waves per block
// LDS layout (float indices):
#define PBF    18432              // hbf = 512*72 shorts = 73728 B at [0,PBF)
                                  // pbf = 512*72 shorts at [PBF, 36864)
#define CANDO  PBF                // cand: 512*12 ushort = 3072 floats (dead before convs)
#define SQO    (PBF + 3072)       // 512 floats (bf16 sq, then exact sq; dead before convs)
#define TBO    (PBF + 3584)       // 12 waves x 16x20 = 3840 floats (dead after filter)
#define WTO    36864              // Wt bf16: 64*72 shorts = 2304 floats
#define LDS_FLOATS 39168
#define LDS_BYTES  (LDS_FLOATS*4) // 156672 B < 160 KiB
// pool/head scratch (pbf region, dead after last conv gather):
#define POOLP  PBF
#define POOLED (PBF + 512)
#define Y1OFF  (PBF + 576)
#define Y2OFF  (PBF + 832)
#define Y3OFF  (PBF + 1088)
#define BIG 1e30f

typedef float v4f __attribute__((ext_vector_type(4)));
typedef short v8s __attribute__((ext_vector_type(8)));

struct Params {
  const float *x;
  const float *W1,*b1,*a1, *W2,*b2,*a2;
  const float *Wc0,*bc0, *Wc1,*bc1, *Wc2,*bc2, *Wc3,*bc3;
  const float *W3,*b3,*a3, *W4,*b4,*a4;
  const float *Wh1,*bh1, *Wh2,*bh2, *Wh3,*bh3, *Wh4,*bh4;
  float *out;
};

// fp32 -> bf16 (RNE) as raw 16-bit
__device__ __forceinline__ unsigned f2bf(float x) {
  union { float f; unsigned u; } cc; cc.f = x;
  unsigned u = cc.u;
  return (u + 0x7FFFu + ((u >> 16) & 1u)) >> 16;
}
__device__ __forceinline__ float bflo(unsigned u) {
  union { unsigned u; float f; } c; c.u = u << 16; return c.f;
}
__device__ __forceinline__ float bfhi(unsigned u) {
  union { unsigned u; float f; } c; c.u = u & 0xffff0000u; return c.f;
}

__device__ __forceinline__ v8s bfrag(const unsigned short* base, int row, int c0) {
  return *(const v8s*)(base + row*SBF + c0);
}

// pack filter-e with its index in the low 9 mantissa bits (|perturb| << bf16 noise;
// candidate SET is all that matters — exact fp32 re-rank decides final order)
__device__ __forceinline__ float packe(float e, int j) {
  return __uint_as_float((__float_as_uint(e) & 0xFFFFFE00u) | (unsigned)j);
}

// sorted-ascending insert via min/max propagation (2 inst/stage)
__device__ __forceinline__ void ins8(float (&b)[8], float v) {
  if (v < b[7]) {
#pragma unroll
    for (int p = 0; p < 8; ++p) {
      float lo = fminf(b[p], v);
      v = fmaxf(b[p], v);
      b[p] = lo;
    }
  }
}
__device__ __forceinline__ void ins12(float (&b)[NCAND], float v) {
  if (v < b[NCAND-1]) {
#pragma unroll
    for (int p = 0; p < NCAND; ++p) {
      float lo = fminf(b[p], v);
      v = fmaxf(b[p], v);
      b[p] = lo;
    }
  }
}

// stage W^T as bf16 into Wt: Wt[col][k] = bf16(W[k*64+col]); tid<512 only
__device__ __forceinline__ void stage_wt(const float* W, unsigned short* wt, int tid) {
  const int col = tid >> 3, ks = (tid & 7) * 8;
  const float* wp = W + col;
  unsigned d[4];
#pragma unroll
  for (int i = 0; i < 4; ++i) {
    unsigned lo = f2bf(wp[(ks + 2*i    ) * NF]);
    unsigned hi = f2bf(wp[(ks + 2*i + 1) * NF]);
    d[i] = lo | (hi << 16);
  }
  *(uint4*)&wt[col*SBF + ks] = make_uint4(d[0], d[1], d[2], d[3]);
}

__global__ __launch_bounds__(NT) void fused_gnn(Params P) {
  extern __shared__ float lds[];
  unsigned short* hbf  = (unsigned short*)lds;
  unsigned short* pbf  = (unsigned short*)&lds[PBF];
  unsigned short* wt   = (unsigned short*)&lds[WTO];
  unsigned short* cand = (unsigned short*)&lds[CANDO];
  const int tid  = threadIdx.x;
  const int g    = blockIdx.x;
  const int rA   = tid;                  // row ownership for tid<512
  const int lane = tid & 63;
  const int w    = tid >> 6;             // wave 0..11
  const int c    = lane & 15;
  const int qq   = lane >> 4;            // 0..3

  const float* xgp = P.x + (size_t)g * NNODE * NF;
  const float4* xg = (const float4*)xgp;

  // ---- stage x[g] as bf16 into hbf ----
#pragma unroll 1
  for (int i = tid; i < NNODE*NF/4; i += NT) {
    float4 v = xg[i];
    int row = i >> 4, k4 = i & 15;
    unsigned lo = f2bf(v.x) | (f2bf(v.y) << 16);
    unsigned hi = f2bf(v.z) | (f2bf(v.w) << 16);
    *(uint2*)&hbf[row*SBF + 4*k4] = make_uint2(lo, hi);
  }
  __syncthreads();

  // ---- filter sq from bf16 values ----
  if (tid < 512) {
    const unsigned* xr32 = (const unsigned*)(hbf + rA*SBF);
    float s = 0.f;
#pragma unroll
    for (int k = 0; k < 32; ++k) {
      unsigned u = xr32[k];
      float f0 = bflo(u), f1 = bfhi(u);
      s = fmaf(f0, f0, s);
      s = fmaf(f1, f1, s);
    }
    lds[SQO + rA] = s;
  }
  __syncthreads();

  // ==== kNN filter: bf16 MFMA Gram + tile transpose + packed lane-local top-8 ====
  {
    float* tb = &lds[TBO + w*16*TBS];
#pragma unroll 1
    for (int tt = w; tt < 32; tt += NW) {
      const int i0 = tt * 16;
      v8s A0 = bfrag(hbf, i0 + c, qq*8);
      v8s A1 = bfrag(hbf, i0 + c, 32 + qq*8);
      const int myrow = i0 + c;

      float d8[8];
#pragma unroll
      for (int m = 0; m < 8; ++m) d8[m] = BIG;

#pragma unroll 1
      for (int jt = 0; jt < 32; ++jt) {
        const int j0 = jt * 16;
        v8s B0 = bfrag(hbf, j0 + c, qq*8);
        v8s B1 = bfrag(hbf, j0 + c, 32 + qq*8);
        v4f acc = {0.f, 0.f, 0.f, 0.f};
        acc = __builtin_amdgcn_mfma_f32_16x16x32_bf16(A0, B0, acc, 0, 0, 0);
        acc = __builtin_amdgcn_mfma_f32_16x16x32_bf16(A1, B1, acc, 0, 0, 0);
#pragma unroll
        for (int r = 0; r < 4; ++r) tb[(qq*4 + r)*TBS + c] = acc[r];
        float4 dv = *(const float4*)&tb[c*TBS + qq*4];
        float4 sv = *(const float4*)&lds[SQO + j0 + qq*4];
        float e0 = fmaf(-2.f, dv.x, sv.x);
        float e1 = fmaf(-2.f, dv.y, sv.y);
        float e2 = fmaf(-2.f, dv.z, sv.z);
        float e3 = fmaf(-2.f, dv.w, sv.w);
        const int jb = j0 + qq*4;
        if (jb     == myrow) e0 = BIG;
        if (jb + 1 == myrow) e1 = BIG;
        if (jb + 2 == myrow) e2 = BIG;
        if (jb + 3 == myrow) e3 = BIG;
        ins8(d8, packe(e0, jb));
        ins8(d8, packe(e1, jb+1));
        ins8(d8, packe(e2, jb+2));
        ins8(d8, packe(e3, jb+3));
      }

      // merge the 4 qq-lanes sharing this row: 2 butterfly stages, capacity 12
      float cd[NCAND];
#pragma unroll
      for (int m = 0; m < 8; ++m) cd[m] = d8[m];
#pragma unroll
      for (int m = 8; m < NCAND; ++m) cd[m] = BIG;
      {
        float pd[8];
#pragma unroll
        for (int s = 0; s < 8; ++s) pd[s] = __shfl_xor(cd[s], 16);
#pragma unroll
        for (int s = 0; s < 8; ++s) ins12(cd, pd[s]);
      }
      {
        float pd[NCAND];
#pragma unroll
        for (int s = 0; s < NCAND; ++s) pd[s] = __shfl_xor(cd[s], 32);
#pragma unroll
        for (int s = 0; s < NCAND; ++s) ins12(cd, pd[s]);
      }
      if (lane < 16) {
#pragma unroll
        for (int s = 0; s < NCAND; ++s)
          cand[(i0 + lane)*NCAND + s] =
            (unsigned short)(__float_as_uint(cd[s]) & 0x1FFu);
      }
    }
  }
  __syncthreads();   // filter done; SQO safe to overwrite

  // ==== exact fp32 refine from GLOBAL x — final indices exact ====
  float4 xr16[16];
  if (tid < 512) {
    const float4* xrow = (const float4*)(xgp + rA*NF);
#pragma unroll
    for (int k4 = 0; k4 < 16; ++k4) xr16[k4] = xrow[k4];
    float s0 = 0.f;
#pragma unroll
    for (int k4 = 0; k4 < 16; ++k4) {
      float4 a = xr16[k4];
      s0 = fmaf(a.x,a.x,s0); s0 = fmaf(a.y,a.y,s0); s0 = fmaf(a.z,a.z,s0); s0 = fmaf(a.w,a.w,s0);
    }
    lds[SQO + rA] = s0;
  }
  __syncthreads();   // exact sq published

  int nbrA[KNN];
  if (tid < 512) {
    float nd[6]; int ni[6];
#pragma unroll
    for (int m = 0; m < 6; ++m) { nd[m] = BIG; ni[m] = 0x7fffffff; }
    int cnd[NCAND];
#pragma unroll
    for (int s = 0; s < NCAND; ++s) cnd[s] = cand[rA*NCAND + s];

#pragma unroll 1
    for (int s = 0; s < NCAND; ++s) {
      int j = cnd[s];
      const float4* xj = (const float4*)(xgp + j*NF);
      float4 aa = {0.f, 0.f, 0.f, 0.f};
#pragma unroll
      for (int k4 = 0; k4 < 16; ++k4) {
        float4 v = xj[k4];
        aa.x = fmaf(xr16[k4].x, v.x, aa.x); aa.y = fmaf(xr16[k4].y, v.y, aa.y);
        aa.z = fmaf(xr16[k4].z, v.z, aa.z); aa.w = fmaf(xr16[k4].w, v.w, aa.w);
      }
      float e = fmaf(-2.f, (aa.x+aa.y)+(aa.z+aa.w), lds[SQO + j]);
      if (e < nd[5] || (e == nd[5] && j < ni[5])) {
#pragma unroll
        for (int pp = 0; pp < 6; ++pp) {
          bool lt = (e < nd[pp]) || (e == nd[pp] && j < ni[pp]);
          float tb2 = nd[pp]; int ti = ni[pp];
          nd[pp] = lt ? e : tb2;  ni[pp] = lt ? j : ti;
          e      = lt ? tb2 : e;  j      = lt ? ti : j;
        }
      }
    }
#pragma unroll
    for (int m = 0; m < 6; ++m) nbrA[m] = ni[m];
  }

  // ==== layers: bf16 MFMA GEMMs over 12 waves ====
  const float* Ws[8]  = {P.W1, P.W2, P.Wc0, P.Wc1, P.Wc2, P.Wc3, P.W3, P.W4};
  const float* bs[8]  = {P.b1, P.b2, P.bc0, P.bc1, P.bc2, P.bc3, P.b3, P.b4};
  const float* as[8]  = {P.a1, P.a2, 0,     0,     0,     0,     P.a3, P.a4};

#pragma unroll 1
  for (int L = 0; L < 8; ++L) {
    const bool isconv = (L >= 2 && L <= 5);
    __syncthreads();                   // prior h stable / prior Wt reads done / cand dead
    if (tid < 512) stage_wt(Ws[L], wt, tid);
    __syncthreads();                   // Wt ready

    v8s B0[4], B1[4];
#pragma unroll
    for (int n = 0; n < 4; ++n) {
      B0[n] = bfrag(wt, n*16 + c, qq*8);
      B1[n] = bfrag(wt, n*16 + c, 32 + qq*8);
    }
    float br[4], ar[4];
    if (!isconv) {
#pragma unroll
      for (int n = 0; n < 4; ++n) { br[n] = bs[L][n*16 + c]; ar[n] = as[L][n*16 + c]; }
    }

#pragma unroll 1
    for (int tt = w; tt < 32; tt += NW) {
      const int i0 = tt * 16;
      v8s A0 = bfrag(hbf, i0 + c, qq*8);
      v8s A1 = bfrag(hbf, i0 + c, 32 + qq*8);
#pragma unroll
      for (int n = 0; n < 4; ++n) {
        v4f acc = {0.f, 0.f, 0.f, 0.f};
        acc = __builtin_amdgcn_mfma_f32_16x16x32_bf16(A0, B0[n], acc, 0, 0, 0);
        acc = __builtin_amdgcn_mfma_f32_16x16x32_bf16(A1, B1[n], acc, 0, 0, 0);
        if (isconv) {
#pragma unroll
          for (int r = 0; r < 4; ++r)
            pbf[(i0 + qq*4 + r)*SBF + n*16 + c] = (unsigned short)f2bf(acc[r]);
        } else {
#pragma unroll
          for (int r = 0; r < 4; ++r) {
            float v = acc[r] + br[n];
            v = v >= 0.f ? v : ar[n]*v;
            hbf[(i0 + qq*4 + r)*SBF + n*16 + c] = (unsigned short)f2bf(v);
          }
        }
      }
    }

    if (isconv) {
      __syncthreads();                 // all p published; all h A-reads done
      if (tid < 512) {
        // gather: h_i + 6b + sum of 6 neighbor p-rows (fp32 accumulate, 64 feats)
        float acc[NF];
        const unsigned* hr = (const unsigned*)&hbf[rA*SBF];
#pragma unroll
        for (int kk = 0; kk < 32; ++kk) {
          unsigned u = hr[kk];
          acc[2*kk]   = bflo(u);
          acc[2*kk+1] = bfhi(u);
        }
        {
          const float4* bp = (const float4*)bs[L];
#pragma unroll
          for (int o4 = 0; o4 < 16; ++o4) {
            float4 bv = bp[o4];
            acc[4*o4]   = fmaf(6.f, bv.x, acc[4*o4]);
            acc[4*o4+1] = fmaf(6.f, bv.y, acc[4*o4+1]);
            acc[4*o4+2] = fmaf(6.f, bv.z, acc[4*o4+2]);
            acc[4*o4+3] = fmaf(6.f, bv.w, acc[4*o4+3]);
          }
        }
#pragma unroll
        for (int mm = 0; mm < KNN; ++mm) {
          const unsigned* pr = (const unsigned*)&pbf[nbrA[mm]*SBF];
#pragma unroll
          for (int kk = 0; kk < 32; ++kk) {
            unsigned u = pr[kk];
            acc[2*kk]   += bflo(u);
            acc[2*kk+1] += bfhi(u);
          }
        }
        unsigned* hw = (unsigned*)&hbf[rA*SBF];
#pragma unroll
        for (int kk = 0; kk < 32; ++kk)
          hw[kk] = f2bf(acc[2*kk]) | (f2bf(acc[2*kk+1]) << 16);
      }
      // own-row write only; next layer's A-reads guarded by loop-top barrier
    }
  }
  __syncthreads();   // h final

  // ---- global add pool: 8 chunks of 64 rows (tid<512) ----
  if (tid < 512) {
    int f = tid & 63, cch = tid >> 6;      // cch 0..7
    int rstart = cch * 64;
    float s = 0.f;
#pragma unroll 1
    for (int r = 0; r < 64; ++r) {
      unsigned u = hbf[(rstart + r)*SBF + f];
      union { unsigned u; float ff; } cv; cv.u = u << 16;
      s += cv.ff;
    }
    lds[POOLP + cch*64 + f] = s;
  }
  __syncthreads();
  if (tid < 64) {
    float pool = 0.f;
#pragma unroll
    for (int cc = 0; cc < 8; ++cc) pool += lds[POOLP + cc*64 + tid];
    lds[POOLED + tid] = pool;
  }
  __syncthreads();

  // ---- head MLP (fp32) ----
  if (tid < 256) {
    float acc = P.bh1[tid];
#pragma unroll 4
    for (int k = 0; k < 64; ++k) acc = fmaf(lds[POOLED+k], P.Wh1[k*256 + tid], acc);
    lds[Y1OFF + tid] = acc >= 0.f ? acc : 0.2f*acc;
  }
  __syncthreads();
  if (tid < 256) {
    float acc = P.bh2[tid];
#pragma unroll 4
    for (int k = 0; k < 256; ++k) acc = fmaf(lds[Y1OFF+k], P.Wh2[k*256 + tid], acc);
    lds[Y2OFF + tid] = acc >= 0.f ? acc : 0.2f*acc;
  }
  __syncthreads();
  if (tid < 64) {
    float acc = P.bh3[tid];
#pragma unroll 4
    for (int k = 0; k < 256; ++k) acc = fmaf(lds[Y2OFF+k], P.Wh3[k*64 + tid], acc);
    lds[Y3OFF + tid] = acc >= 0.f ? acc : 0.2f*acc;
  }
  __syncthreads();
  if (tid == 0) {
    float acc = P.bh4[0];
#pragma unroll 4
    for (int k = 0; k < 64; ++k) acc = fmaf(lds[Y3OFF+k], P.Wh4[k], acc);
    P.out[g] = acc;
  }
}

extern "C" void kernel_launch(void* const* d_in, const int* in_sizes, int n_in,
                              void* d_out, int out_size, void* d_ws, size_t ws_size,
                              hipStream_t stream) {
  Params P;
  P.x   = (const float*)d_in[0];
  P.W1  = (const float*)d_in[1];  P.b1  = (const float*)d_in[2];  P.a1 = (const float*)d_in[3];
  P.W2  = (const float*)d_in[4];  P.b2  = (const float*)d_in[5];  P.a2 = (const float*)d_in[6];
  P.Wc0 = (const float*)d_in[7];  P.bc0 = (const float*)d_in[8];
  P.Wc1 = (const float*)d_in[9];  P.bc1 = (const float*)d_in[10];
  P.Wc2 = (const float*)d_in[11]; P.bc2 = (const float*)d_in[12];
  P.Wc3 = (const float*)d_in[13]; P.bc3 = (const float*)d_in[14];
  P.W3  = (const float*)d_in[15]; P.b3  = (const float*)d_in[16]; P.a3 = (const float*)d_in[17];
  P.W4  = (const float*)d_in[18]; P.b4  = (const float*)d_in[19]; P.a4 = (const float*)d_in[20];
  P.Wh1 = (const float*)d_in[21]; P.bh1 = (const float*)d_in[22];
  P.Wh2 = (const float*)d_in[23]; P.bh2 = (const float*)d_in[24];
  P.Wh3 = (const float*)d_in[25]; P.bh3 = (const float*)d_in[26];
  P.Wh4 = (const float*)d_in[27]; P.bh4 = (const float*)d_in[28];
  P.out = (float*)d_out;

  (void)hipFuncSetAttribute(reinterpret_cast<const void*>(fused_gnn),
                            hipFuncAttributeMaxDynamicSharedMemorySize, LDS_BYTES);

  fused_gnn<<<NGRAPH, NT, LDS_BYTES, stream>>>(P);
}